// Round 16
// baseline (106.993 us; speedup 1.0000x reference)
//
#include <hip/hip_runtime.h>
#include <hip/hip_fp16.h>
#include <math.h>

#define N_NODES   100000
#define N_EDGES   1000000
#define N_GRAPHS  256
#define NUM_TYPES 200
#define EMB       64
#define HID       32
#define BSHIFT    8
#define BSTRIDE   256
#define NBUCK     391     // ceil(100000/256)
#define EPB       4096
#define NCHUNK    245     // ceil(1e6/4096)
#define MAXBE     4096    // padded per-bucket capacity (mean 2560, +30 sigma)
#define SRCBITS   17
#define SRCMASK   0x1FFFF
#define ELOC      1024    // staged edges per gather1 block (32 nodes, mean 320)

// ---------------- phase 1: chunk-local bucket sort (+ table + pooled-zero) ----------------

__global__ __launch_bounds__(512) void k_bin(const int* __restrict__ src,
                                             const int* __restrict__ dst,
                                             int* __restrict__ binned,
                                             int* __restrict__ counts,
                                             int* __restrict__ locg,
                                             const float* __restrict__ emb,
                                             const float* __restrict__ W1,
                                             float* __restrict__ table,
                                             float* __restrict__ pooled) {
    int tid = threadIdx.x, c = blockIdx.x;
    if (c == NCHUNK) {
        for (int t = tid; t < NUM_TYPES * HID; t += 512) {
            int ty = t / HID, j = t % HID;
            float s = 0.f;
            for (int k = 0; k < EMB; ++k) s = fmaf(emb[ty * EMB + k], W1[k * HID + j], s);
            table[t] = s;
        }
        return;
    }
    if (c == NCHUNK + 1) {
        for (int t = tid; t < N_GRAPHS * HID; t += 512) pooled[t] = 0.f;
        return;
    }
    __shared__ int srcl[EPB];
    __shared__ int dstl[EPB];
    __shared__ unsigned short rank16[EPB];
    __shared__ unsigned short perm[EPB];
    __shared__ int cnt[NBUCK];
    __shared__ int loc[NBUCK];
    __shared__ int sA[512], sB[512];
    int base = c * EPB;
    int n = min(EPB, N_EDGES - base);
    if (tid < NBUCK) cnt[tid] = 0;
    __syncthreads();
    for (int t = tid; t < n; t += 512) {
        int s = src[base + t], d = dst[base + t];
        srcl[t] = s; dstl[t] = d;
        rank16[t] = (unsigned short)atomicAdd(&cnt[d >> BSHIFT], 1);
    }
    __syncthreads();
    sA[tid] = (tid < NBUCK) ? cnt[tid] : 0;
    __syncthreads();
    int* in = sA; int* ot = sB;
    for (int off = 1; off < 512; off <<= 1) {
        ot[tid] = in[tid] + (tid >= off ? in[tid - off] : 0);
        __syncthreads();
        int* tmp = in; in = ot; ot = tmp;
    }
    if (tid < NBUCK) loc[tid] = in[tid] - cnt[tid];
    __syncthreads();
    for (int t = tid; t < n; t += 512) {
        int b = dstl[t] >> BSHIFT;
        perm[loc[b] + rank16[t]] = (unsigned short)t;
    }
    __syncthreads();
    for (int t = tid; t < n; t += 512) {
        int e = perm[t];
        binned[base + t] = ((dstl[e] & (BSTRIDE - 1)) << SRCBITS) | srcl[e];
    }
    if (tid < NBUCK) {
        counts[c * NBUCK + tid] = cnt[tid];
        locg[c * NBUCK + tid] = loc[tid];
    }
}

// ---------------- phase 2: per-bucket node sort -> padded ssrc + nmeta ----------------

__global__ __launch_bounds__(512) void k_csr(const int* __restrict__ binned,
                                             const int* __restrict__ counts,
                                             const int* __restrict__ locg,
                                             const int* __restrict__ ids,
                                             int* __restrict__ ssrc,
                                             int2* __restrict__ nodeinfo,
                                             int4* __restrict__ nmeta) {
    __shared__ int pk[MAXBE];
    __shared__ unsigned char dl[MAXBE];
    __shared__ unsigned short rank16[MAXBE];
    __shared__ unsigned short perm[MAXBE];
    __shared__ int degL[BSTRIDE];
    __shared__ int loc[BSTRIDE];
    __shared__ int sA[512], sB[512];
    __shared__ int ccnt[NCHUNK];
    __shared__ int cloc[NCHUNK];
    __shared__ int cbase[NCHUNK];
    int tid = threadIdx.x, b = blockIdx.x;

    if (tid < NCHUNK) {
        ccnt[tid] = counts[tid * NBUCK + b];
        cloc[tid] = locg[tid * NBUCK + b];
    }
    __syncthreads();
    sA[tid] = (tid < NCHUNK) ? ccnt[tid] : 0;
    __syncthreads();
    int* in = sA; int* ot = sB;
    for (int off = 1; off < 512; off <<= 1) {
        ot[tid] = in[tid] + (tid >= off ? in[tid - off] : 0);
        __syncthreads();
        int* tmp = in; in = ot; ot = tmp;
    }
    if (tid < NCHUNK) cbase[tid] = in[tid] - ccnt[tid];
    __syncthreads();
    int n = min(in[NCHUNK - 1], MAXBE);
    // copy segments into pk: 2 threads per chunk halves the serial depth
    for (int w = tid; w < NCHUNK * 2; w += 512) {
        int c = w >> 1, half = w & 1;
        int m = ccnt[c];
        int gsrc = c * EPB + cloc[c];
        int ldst = cbase[c];
        for (int j = half; j < m; j += 2) pk[ldst + j] = binned[gsrc + j];
    }
    if (tid < BSTRIDE) degL[tid] = 0;
    __syncthreads();

    for (int t = tid; t < n; t += 512) {
        int d = pk[t] >> SRCBITS;
        dl[t] = (unsigned char)d;
        rank16[t] = (unsigned short)atomicAdd(&degL[d], 1);
    }
    __syncthreads();
    if (tid < BSTRIDE) sA[tid] = degL[tid];
    __syncthreads();
    in = sA; ot = sB;
    for (int off = 1; off < BSTRIDE; off <<= 1) {
        if (tid < BSTRIDE) ot[tid] = in[tid] + (tid >= off ? in[tid - off] : 0);
        __syncthreads();
        int* tmp = in; in = ot; ot = tmp;
    }
    if (tid < BSTRIDE) loc[tid] = in[tid] - degL[tid];
    __syncthreads();
    for (int t = tid; t < n; t += 512)
        perm[loc[dl[t]] + rank16[t]] = (unsigned short)t;
    __syncthreads();
    int e0 = b * MAXBE;
    for (int t = tid; t < n; t += 512)
        ssrc[e0 + t] = pk[perm[t]] & SRCMASK;
    if (tid < BSTRIDE) {
        int i = b * BSTRIDE + tid;
        if (i < N_NODES) {
            float dv = rsqrtf((float)degL[tid] + 1.0f);
            nodeinfo[i] = make_int2(ids[i], __float_as_int(dv));
            nmeta[i] = make_int4(e0 + loc[tid], degL[tid], ids[i], __float_as_int(dv));
        }
    }
}

// ---------------- feature pipeline ----------------

// Layer 1 + layer-2 producer, fused; LDS staging; 16-deep per-node loop.
__global__ __launch_bounds__(256) void k_gather1(
        const int2* __restrict__ nodeinfo, const int4* __restrict__ nmeta,
        const float* __restrict__ table, const int* __restrict__ ssrc,
        const float* __restrict__ b1, const float* __restrict__ W2,
        uint2* __restrict__ Y2h) {
    __shared__ float w[HID * HID];
    __shared__ unsigned int eloc[ELOC];
    int tid = threadIdx.x;
    for (int k = tid; k < HID * HID; k += 256) w[k] = W2[k];

    int i0 = (blockIdx.x * 256) >> 3;
    int4 m0 = nmeta[i0];
    int4 m31 = nmeta[i0 + 31];
    int eb0 = m0.x;
    int ne = m31.x + m31.y - eb0;
    bool fits = (ne <= ELOC);
    if (fits) {
        for (int t = tid; t < ne; t += 256) {
            int s = ssrc[eb0 + t];
            int2 ni = nodeinfo[s];
            eloc[t] = ((unsigned)ni.x << 16) |
                      __half_as_ushort(__float2half(__int_as_float(ni.y)));
        }
    }
    __syncthreads();

    int t = blockIdx.x * 256 + tid;
    int i = t >> 3, p = t & 7;
    const float4* tab4 = (const float4*)table;

    int4 nm = nmeta[i];
    int s0 = nm.x, n = nm.y;
    int l0 = s0 - eb0;
    float di = __int_as_float(nm.w);
    float4 acc = tab4[nm.z * 8 + p];
    acc.x *= di; acc.y *= di; acc.z *= di; acc.w *= di;

    if (fits) {
        for (int e = 0; e < n; e += 16) {
            unsigned int ei[16];
#pragma unroll
            for (int u = 0; u < 16; ++u) {
                int idx = e + u; idx = (idx > n - 1) ? n - 1 : idx;
                ei[u] = eloc[l0 + idx];
            }
#pragma unroll
            for (int u = 0; u < 16; ++u) {
                float ds = (e + u < n)
                    ? __half2float(__ushort_as_half((unsigned short)(ei[u] & 0xFFFF))) : 0.f;
                float4 v = tab4[(ei[u] >> 16) * 8 + p];
                acc.x = fmaf(v.x, ds, acc.x);
                acc.y = fmaf(v.y, ds, acc.y);
                acc.z = fmaf(v.z, ds, acc.z);
                acc.w = fmaf(v.w, ds, acc.w);
            }
        }
    } else {                                         // fallback (never expected)
        for (int e = 0; e < n; ++e) {
            int s = ssrc[s0 + e];
            int2 ni = nodeinfo[s];
            float ds = __half2float(__float2half(__int_as_float(ni.y)));
            float4 v = tab4[ni.x * 8 + p];
            acc.x = fmaf(v.x, ds, acc.x);
            acc.y = fmaf(v.y, ds, acc.y);
            acc.z = fmaf(v.z, ds, acc.z);
            acc.w = fmaf(v.w, ds, acc.w);
        }
    }
    float4 bb = ((const float4*)b1)[p];
    float4 h;
    h.x = fmaxf(fmaf(di, acc.x, bb.x), 0.f);
    h.y = fmaxf(fmaf(di, acc.y, bb.y), 0.f);
    h.z = fmaxf(fmaf(di, acc.z, bb.z), 0.f);
    h.w = fmaxf(fmaf(di, acc.w, bb.w), 0.f);

    float o0 = 0.f, o1 = 0.f, o2 = 0.f, o3 = 0.f;
    const float4* w4 = (const float4*)w;
#pragma unroll
    for (int q = 0; q < 8; ++q) {
        float4 hq;
        hq.x = __shfl(h.x, q, 8);
        hq.y = __shfl(h.y, q, 8);
        hq.z = __shfl(h.z, q, 8);
        hq.w = __shfl(h.w, q, 8);
        float4 w0 = w4[(4 * q + 0) * 8 + p];
        float4 w1 = w4[(4 * q + 1) * 8 + p];
        float4 w2 = w4[(4 * q + 2) * 8 + p];
        float4 w3 = w4[(4 * q + 3) * 8 + p];
        o0 = fmaf(hq.x, w0.x, o0); o1 = fmaf(hq.x, w0.y, o1); o2 = fmaf(hq.x, w0.z, o2); o3 = fmaf(hq.x, w0.w, o3);
        o0 = fmaf(hq.y, w1.x, o0); o1 = fmaf(hq.y, w1.y, o1); o2 = fmaf(hq.y, w1.z, o2); o3 = fmaf(hq.y, w1.w, o3);
        o0 = fmaf(hq.z, w2.x, o0); o1 = fmaf(hq.z, w2.y, o1); o2 = fmaf(hq.z, w2.z, o2); o3 = fmaf(hq.z, w2.w, o3);
        o0 = fmaf(hq.w, w3.x, o0); o1 = fmaf(hq.w, w3.y, o1); o2 = fmaf(hq.w, w3.z, o2); o3 = fmaf(hq.w, w3.w, o3);
    }
    __half2 h01 = __halves2half2(__float2half(o0 * di), __float2half(o1 * di));
    __half2 h23 = __halves2half2(__float2half(o2 * di), __float2half(o3 * di));
    uint2 wv;
    wv.x = *(unsigned int*)&h01;
    wv.y = *(unsigned int*)&h23;
    Y2h[i * 8 + p] = wv;
}

// Layer 2 (f16 payload) + fused mean-pool; 16-deep pipelined.
__global__ __launch_bounds__(256) void k_gather2(
        const uint2* __restrict__ Y2h, const int4* __restrict__ nmeta,
        const int* __restrict__ ssrc, const float* __restrict__ b2,
        const int* __restrict__ batch, float* __restrict__ pooled) {
    __shared__ float lp[32][HID];
    for (int k = threadIdx.x; k < 32 * HID; k += 256) ((float*)lp)[k] = 0.f;
    __syncthreads();

    int t = blockIdx.x * 256 + threadIdx.x;
    int i = t >> 3, p = t & 7;
    int i0 = (blockIdx.x * 256) >> 3;
    int gFirst = batch[i0];

    uint2 selfv = Y2h[i * 8 + p];
    float2 sa = __half22float2(*(__half2*)&selfv.x);
    float2 sb = __half22float2(*(__half2*)&selfv.y);
    float4 acc = make_float4(sa.x, sa.y, sb.x, sb.y);

    int4 nm = nmeta[i];
    int s0 = nm.x, n = nm.y;
    for (int e = 0; e < n; e += 16) {
        int ss[16];
#pragma unroll
        for (int u = 0; u < 16; ++u) {
            int idx = e + u; idx = (idx > n - 1) ? n - 1 : idx;
            ss[u] = ssrc[s0 + idx];
        }
        uint2 v[16];
#pragma unroll
        for (int u = 0; u < 16; ++u) v[u] = Y2h[ss[u] * 8 + p];
#pragma unroll
        for (int u = 0; u < 16; ++u) {
            float wg = (e + u < n) ? 1.f : 0.f;
            float2 fa = __half22float2(*(__half2*)&v[u].x);
            float2 fb = __half22float2(*(__half2*)&v[u].y);
            acc.x = fmaf(fa.x, wg, acc.x);
            acc.y = fmaf(fa.y, wg, acc.y);
            acc.z = fmaf(fb.x, wg, acc.z);
            acc.w = fmaf(fb.y, wg, acc.w);
        }
    }
    float di = __int_as_float(nm.w);
    float4 bb = ((const float4*)b2)[p];
    float4 h;
    h.x = fmaxf(fmaf(di, acc.x, bb.x), 0.f);
    h.y = fmaxf(fmaf(di, acc.y, bb.y), 0.f);
    h.z = fmaxf(fmaf(di, acc.z, bb.z), 0.f);
    h.w = fmaxf(fmaf(di, acc.w, bb.w), 0.f);

    int gl = batch[i] - gFirst;
    atomicAdd(&lp[gl][p * 4 + 0], h.x);
    atomicAdd(&lp[gl][p * 4 + 1], h.y);
    atomicAdd(&lp[gl][p * 4 + 2], h.z);
    atomicAdd(&lp[gl][p * 4 + 3], h.w);
    __syncthreads();

    int gLast = batch[i0 + 31];
    int ng = gLast - gFirst + 1;
    for (int k = threadIdx.x; k < ng * HID; k += 256) {
        float v = lp[k / HID][k % HID];
        if (v != 0.f) atomicAdd(&pooled[(gFirst + k / HID) * HID + (k % HID)], v);
    }
}

// head: mean (counts via binary search) -> relu(@Wc1+bc1) -> sigmoid(@Wc2+bc2)
__global__ void k_head(const float* __restrict__ pooled, const int* __restrict__ batch,
                       const float* __restrict__ Wc1, const float* __restrict__ bc1,
                       const float* __restrict__ Wc2, const float* __restrict__ bc2,
                       float* __restrict__ out) {
    int g = blockIdx.x * blockDim.x + threadIdx.x;
    if (g >= N_GRAPHS) return;
    int lo = 0, hi = N_NODES;
    while (lo < hi) { int mid = (lo + hi) >> 1; if (batch[mid] < g) lo = mid + 1; else hi = mid; }
    int start = lo;
    hi = N_NODES;
    while (lo < hi) { int mid = (lo + hi) >> 1; if (batch[mid] < g + 1) lo = mid + 1; else hi = mid; }
    int end = lo;
    float inv = 1.0f / fmaxf((float)(end - start), 1.0f);
    float m[HID];
    for (int j = 0; j < HID; ++j) m[j] = pooled[g * HID + j] * inv;
    float hc[16];
    for (int j = 0; j < 16; ++j) {
        float s = bc1[j];
        for (int k = 0; k < HID; ++k) s = fmaf(m[k], Wc1[k * 16 + j], s);
        hc[j] = fmaxf(s, 0.f);
    }
    float s = bc2[0];
    for (int k = 0; k < 16; ++k) s = fmaf(hc[k], Wc2[k], s);
    out[g] = 1.0f / (1.0f + expf(-s));
}

// ---------------- launch ----------------

extern "C" void kernel_launch(void* const* d_in, const int* in_sizes, int n_in,
                              void* d_out, int out_size, void* d_ws, size_t ws_size,
                              hipStream_t stream) {
    const int*   ids  = (const int*)d_in[0];
    const int*   src  = (const int*)d_in[1];
    const int*   dst  = ((const int*)d_in[1]) + N_EDGES;
    const int*   batch = (const int*)d_in[2];
    const float* emb  = (const float*)d_in[3];
    const float* W1   = (const float*)d_in[4];
    const float* b1   = (const float*)d_in[5];
    const float* W2   = (const float*)d_in[6];
    const float* b2   = (const float*)d_in[7];
    const float* Wc1  = (const float*)d_in[8];
    const float* bc1  = (const float*)d_in[9];
    const float* Wc2  = (const float*)d_in[10];
    const float* bc2  = (const float*)d_in[11];
    float* out = (float*)d_out;

    // workspace layout — int-element offsets; all sections multiples of 4 ints.
    int* W = (int*)d_ws;
    size_t o = 0;
    uint2* Y2h      = (uint2*)(W + o);        o += 1600000;
    int*   binned   = W + o;                  o += N_EDGES;
    int*   ssrc     = W + o;                  o += NBUCK * MAXBE;
    int2*  nodeinfo = (int2*)(W + o);         o += 2 * N_NODES;
    int4*  nmeta    = (int4*)(W + o);         o += 4 * N_NODES;
    int*   counts   = W + o;                  o += NCHUNK * NBUCK + 1;
    o = (o + 3) & ~(size_t)3;
    int*   locg     = W + o;                  o += NCHUNK * NBUCK;
    o = (o + 3) & ~(size_t)3;
    float* table    = (float*)(W + o);        o += NUM_TYPES * HID;
    float* pooled   = (float*)(W + o);

    const int B = 256;
    const int gNode8 = (N_NODES * 8) / B;       // exact: 3125

    k_bin<<<NCHUNK + 2, 512, 0, stream>>>(src, dst, binned, counts, locg,
                                          emb, W1, table, pooled);
    k_csr<<<NBUCK, 512, 0, stream>>>(binned, counts, locg, ids, ssrc, nodeinfo, nmeta);
    k_gather1<<<gNode8, B, 0, stream>>>(nodeinfo, nmeta, table, ssrc, b1, W2, Y2h);
    k_gather2<<<gNode8, B, 0, stream>>>((const uint2*)Y2h, nmeta, ssrc, b2, batch, pooled);
    k_head<<<1, N_GRAPHS, 0, stream>>>(pooled, batch, Wc1, bc1, Wc2, bc2, out);
}

// Round 17
// 104.956 us; speedup vs baseline: 1.0194x; 1.0194x over previous
//
#include <hip/hip_runtime.h>
#include <hip/hip_fp16.h>
#include <math.h>

#define N_NODES   100000
#define N_EDGES   1000000
#define N_GRAPHS  256
#define NUM_TYPES 200
#define EMB       64
#define HID       32
#define BSHIFT    8
#define BSTRIDE   256
#define NBUCK     391     // ceil(100000/256)
#define EPB       4096
#define NCHUNK    245     // ceil(1e6/4096)
#define MAXBE     4096    // padded per-bucket capacity (mean 2560, +30 sigma)
#define SRCBITS   17
#define SRCMASK   0x1FFFF
#define ELOC      1024    // staged edges per gather1 block (32 nodes, mean 320)

// ---------------- phase 1: chunk-local bucket sort (+ table + pooled-zero) ----------------

__global__ __launch_bounds__(512) void k_bin(const int* __restrict__ src,
                                             const int* __restrict__ dst,
                                             int* __restrict__ binned,
                                             int* __restrict__ counts,
                                             int* __restrict__ locg,
                                             const float* __restrict__ emb,
                                             const float* __restrict__ W1,
                                             float* __restrict__ table,
                                             float* __restrict__ pooled) {
    int tid = threadIdx.x, c = blockIdx.x;
    if (c == NCHUNK) {
        for (int t = tid; t < NUM_TYPES * HID; t += 512) {
            int ty = t / HID, j = t % HID;
            float s = 0.f;
            for (int k = 0; k < EMB; ++k) s = fmaf(emb[ty * EMB + k], W1[k * HID + j], s);
            table[t] = s;
        }
        return;
    }
    if (c == NCHUNK + 1) {
        for (int t = tid; t < N_GRAPHS * HID; t += 512) pooled[t] = 0.f;
        return;
    }
    __shared__ int srcl[EPB];
    __shared__ int dstl[EPB];
    __shared__ unsigned short rank16[EPB];
    __shared__ unsigned short perm[EPB];
    __shared__ int cnt[NBUCK];
    __shared__ int loc[NBUCK];
    __shared__ int sA[512], sB[512];
    int base = c * EPB;
    int n = min(EPB, N_EDGES - base);
    if (tid < NBUCK) cnt[tid] = 0;
    __syncthreads();
    for (int t = tid; t < n; t += 512) {
        int s = src[base + t], d = dst[base + t];
        srcl[t] = s; dstl[t] = d;
        rank16[t] = (unsigned short)atomicAdd(&cnt[d >> BSHIFT], 1);
    }
    __syncthreads();
    sA[tid] = (tid < NBUCK) ? cnt[tid] : 0;
    __syncthreads();
    int* in = sA; int* ot = sB;
    for (int off = 1; off < 512; off <<= 1) {
        ot[tid] = in[tid] + (tid >= off ? in[tid - off] : 0);
        __syncthreads();
        int* tmp = in; in = ot; ot = tmp;
    }
    if (tid < NBUCK) loc[tid] = in[tid] - cnt[tid];
    __syncthreads();
    for (int t = tid; t < n; t += 512) {
        int b = dstl[t] >> BSHIFT;
        perm[loc[b] + rank16[t]] = (unsigned short)t;
    }
    __syncthreads();
    for (int t = tid; t < n; t += 512) {
        int e = perm[t];
        binned[base + t] = ((dstl[e] & (BSTRIDE - 1)) << SRCBITS) | srcl[e];
    }
    if (tid < NBUCK) {
        counts[c * NBUCK + tid] = cnt[tid];
        locg[c * NBUCK + tid] = loc[tid];
    }
}

// ---------------- phase 2: per-bucket node sort -> padded ssrc + nmeta ----------------

__global__ __launch_bounds__(512) void k_csr(const int* __restrict__ binned,
                                             const int* __restrict__ counts,
                                             const int* __restrict__ locg,
                                             const int* __restrict__ ids,
                                             int* __restrict__ ssrc,
                                             int2* __restrict__ nodeinfo,
                                             int4* __restrict__ nmeta) {
    __shared__ int pk[MAXBE];
    __shared__ unsigned char dl[MAXBE];
    __shared__ unsigned short rank16[MAXBE];
    __shared__ unsigned short perm[MAXBE];
    __shared__ int degL[BSTRIDE];
    __shared__ int loc[BSTRIDE];
    __shared__ int sA[512], sB[512];
    __shared__ int ccnt[NCHUNK];
    __shared__ int cloc[NCHUNK];
    __shared__ int cbase[NCHUNK];
    int tid = threadIdx.x, b = blockIdx.x;

    if (tid < NCHUNK) {
        ccnt[tid] = counts[tid * NBUCK + b];
        cloc[tid] = locg[tid * NBUCK + b];
    }
    __syncthreads();
    sA[tid] = (tid < NCHUNK) ? ccnt[tid] : 0;
    __syncthreads();
    int* in = sA; int* ot = sB;
    for (int off = 1; off < 512; off <<= 1) {
        ot[tid] = in[tid] + (tid >= off ? in[tid - off] : 0);
        __syncthreads();
        int* tmp = in; in = ot; ot = tmp;
    }
    if (tid < NCHUNK) cbase[tid] = in[tid] - ccnt[tid];
    __syncthreads();
    int n = min(in[NCHUNK - 1], MAXBE);
    // copy segments into pk: 2 threads per chunk halves the serial depth
    for (int w = tid; w < NCHUNK * 2; w += 512) {
        int c = w >> 1, half = w & 1;
        int m = ccnt[c];
        int gsrc = c * EPB + cloc[c];
        int ldst = cbase[c];
        for (int j = half; j < m; j += 2) pk[ldst + j] = binned[gsrc + j];
    }
    if (tid < BSTRIDE) degL[tid] = 0;
    __syncthreads();

    for (int t = tid; t < n; t += 512) {
        int d = pk[t] >> SRCBITS;
        dl[t] = (unsigned char)d;
        rank16[t] = (unsigned short)atomicAdd(&degL[d], 1);
    }
    __syncthreads();
    if (tid < BSTRIDE) sA[tid] = degL[tid];
    __syncthreads();
    in = sA; ot = sB;
    for (int off = 1; off < BSTRIDE; off <<= 1) {
        if (tid < BSTRIDE) ot[tid] = in[tid] + (tid >= off ? in[tid - off] : 0);
        __syncthreads();
        int* tmp = in; in = ot; ot = tmp;
    }
    if (tid < BSTRIDE) loc[tid] = in[tid] - degL[tid];
    __syncthreads();
    for (int t = tid; t < n; t += 512)
        perm[loc[dl[t]] + rank16[t]] = (unsigned short)t;
    __syncthreads();
    int e0 = b * MAXBE;
    for (int t = tid; t < n; t += 512)
        ssrc[e0 + t] = pk[perm[t]] & SRCMASK;
    if (tid < BSTRIDE) {
        int i = b * BSTRIDE + tid;
        if (i < N_NODES) {
            float dv = rsqrtf((float)degL[tid] + 1.0f);
            nodeinfo[i] = make_int2(ids[i], __float_as_int(dv));
            nmeta[i] = make_int4(e0 + loc[tid], degL[tid], ids[i], __float_as_int(dv));
        }
    }
}

// ---------------- feature pipeline ----------------

// Layer 1 + layer-2 producer, fused; LDS staging; 8-deep per-node loop.
__global__ __launch_bounds__(256) void k_gather1(
        const int2* __restrict__ nodeinfo, const int4* __restrict__ nmeta,
        const float* __restrict__ table, const int* __restrict__ ssrc,
        const float* __restrict__ b1, const float* __restrict__ W2,
        uint2* __restrict__ Y2h) {
    __shared__ float w[HID * HID];
    __shared__ unsigned int eloc[ELOC];
    int tid = threadIdx.x;
    for (int k = tid; k < HID * HID; k += 256) w[k] = W2[k];

    int i0 = (blockIdx.x * 256) >> 3;
    int4 m0 = nmeta[i0];
    int4 m31 = nmeta[i0 + 31];
    int eb0 = m0.x;
    int ne = m31.x + m31.y - eb0;
    bool fits = (ne <= ELOC);
    if (fits) {
        for (int t = tid; t < ne; t += 256) {
            int s = ssrc[eb0 + t];
            int2 ni = nodeinfo[s];
            eloc[t] = ((unsigned)ni.x << 16) |
                      __half_as_ushort(__float2half(__int_as_float(ni.y)));
        }
    }
    __syncthreads();

    int t = blockIdx.x * 256 + tid;
    int i = t >> 3, p = t & 7;
    const float4* tab4 = (const float4*)table;

    int4 nm = nmeta[i];
    int s0 = nm.x, n = nm.y;
    int l0 = s0 - eb0;
    float di = __int_as_float(nm.w);
    float4 acc = tab4[nm.z * 8 + p];
    acc.x *= di; acc.y *= di; acc.z *= di; acc.w *= di;

    if (fits) {
        for (int e = 0; e < n; e += 8) {
            unsigned int ei[8];
#pragma unroll
            for (int u = 0; u < 8; ++u) {
                int idx = e + u; idx = (idx > n - 1) ? n - 1 : idx;
                ei[u] = eloc[l0 + idx];
            }
#pragma unroll
            for (int u = 0; u < 8; ++u) {
                float ds = (e + u < n)
                    ? __half2float(__ushort_as_half((unsigned short)(ei[u] & 0xFFFF))) : 0.f;
                float4 v = tab4[(ei[u] >> 16) * 8 + p];
                acc.x = fmaf(v.x, ds, acc.x);
                acc.y = fmaf(v.y, ds, acc.y);
                acc.z = fmaf(v.z, ds, acc.z);
                acc.w = fmaf(v.w, ds, acc.w);
            }
        }
    } else {                                         // fallback (never expected)
        for (int e = 0; e < n; ++e) {
            int s = ssrc[s0 + e];
            int2 ni = nodeinfo[s];
            float ds = __half2float(__float2half(__int_as_float(ni.y)));
            float4 v = tab4[ni.x * 8 + p];
            acc.x = fmaf(v.x, ds, acc.x);
            acc.y = fmaf(v.y, ds, acc.y);
            acc.z = fmaf(v.z, ds, acc.z);
            acc.w = fmaf(v.w, ds, acc.w);
        }
    }
    float4 bb = ((const float4*)b1)[p];
    float4 h;
    h.x = fmaxf(fmaf(di, acc.x, bb.x), 0.f);
    h.y = fmaxf(fmaf(di, acc.y, bb.y), 0.f);
    h.z = fmaxf(fmaf(di, acc.z, bb.z), 0.f);
    h.w = fmaxf(fmaf(di, acc.w, bb.w), 0.f);

    float o0 = 0.f, o1 = 0.f, o2 = 0.f, o3 = 0.f;
    const float4* w4 = (const float4*)w;
#pragma unroll
    for (int q = 0; q < 8; ++q) {
        float4 hq;
        hq.x = __shfl(h.x, q, 8);
        hq.y = __shfl(h.y, q, 8);
        hq.z = __shfl(h.z, q, 8);
        hq.w = __shfl(h.w, q, 8);
        float4 w0 = w4[(4 * q + 0) * 8 + p];
        float4 w1 = w4[(4 * q + 1) * 8 + p];
        float4 w2 = w4[(4 * q + 2) * 8 + p];
        float4 w3 = w4[(4 * q + 3) * 8 + p];
        o0 = fmaf(hq.x, w0.x, o0); o1 = fmaf(hq.x, w0.y, o1); o2 = fmaf(hq.x, w0.z, o2); o3 = fmaf(hq.x, w0.w, o3);
        o0 = fmaf(hq.y, w1.x, o0); o1 = fmaf(hq.y, w1.y, o1); o2 = fmaf(hq.y, w1.z, o2); o3 = fmaf(hq.y, w1.w, o3);
        o0 = fmaf(hq.z, w2.x, o0); o1 = fmaf(hq.z, w2.y, o1); o2 = fmaf(hq.z, w2.z, o2); o3 = fmaf(hq.z, w2.w, o3);
        o0 = fmaf(hq.w, w3.x, o0); o1 = fmaf(hq.w, w3.y, o1); o2 = fmaf(hq.w, w3.z, o2); o3 = fmaf(hq.w, w3.w, o3);
    }
    __half2 h01 = __halves2half2(__float2half(o0 * di), __float2half(o1 * di));
    __half2 h23 = __halves2half2(__float2half(o2 * di), __float2half(o3 * di));
    uint2 wv;
    wv.x = *(unsigned int*)&h01;
    wv.y = *(unsigned int*)&h23;
    Y2h[i * 8 + p] = wv;
}

// Layer 2 (f16 payload) + fused mean-pool; 8-deep pipelined.
__global__ __launch_bounds__(256) void k_gather2(
        const uint2* __restrict__ Y2h, const int4* __restrict__ nmeta,
        const int* __restrict__ ssrc, const float* __restrict__ b2,
        const int* __restrict__ batch, float* __restrict__ pooled) {
    __shared__ float lp[32][HID];
    for (int k = threadIdx.x; k < 32 * HID; k += 256) ((float*)lp)[k] = 0.f;
    __syncthreads();

    int t = blockIdx.x * 256 + threadIdx.x;
    int i = t >> 3, p = t & 7;
    int i0 = (blockIdx.x * 256) >> 3;
    int gFirst = batch[i0];

    uint2 selfv = Y2h[i * 8 + p];
    float2 sa = __half22float2(*(__half2*)&selfv.x);
    float2 sb = __half22float2(*(__half2*)&selfv.y);
    float4 acc = make_float4(sa.x, sa.y, sb.x, sb.y);

    int4 nm = nmeta[i];
    int s0 = nm.x, n = nm.y;
    for (int e = 0; e < n; e += 8) {
        int ss[8];
#pragma unroll
        for (int u = 0; u < 8; ++u) {
            int idx = e + u; idx = (idx > n - 1) ? n - 1 : idx;
            ss[u] = ssrc[s0 + idx];
        }
        uint2 v[8];
#pragma unroll
        for (int u = 0; u < 8; ++u) v[u] = Y2h[ss[u] * 8 + p];
#pragma unroll
        for (int u = 0; u < 8; ++u) {
            float wg = (e + u < n) ? 1.f : 0.f;
            float2 fa = __half22float2(*(__half2*)&v[u].x);
            float2 fb = __half22float2(*(__half2*)&v[u].y);
            acc.x = fmaf(fa.x, wg, acc.x);
            acc.y = fmaf(fa.y, wg, acc.y);
            acc.z = fmaf(fb.x, wg, acc.z);
            acc.w = fmaf(fb.y, wg, acc.w);
        }
    }
    float di = __int_as_float(nm.w);
    float4 bb = ((const float4*)b2)[p];
    float4 h;
    h.x = fmaxf(fmaf(di, acc.x, bb.x), 0.f);
    h.y = fmaxf(fmaf(di, acc.y, bb.y), 0.f);
    h.z = fmaxf(fmaf(di, acc.z, bb.z), 0.f);
    h.w = fmaxf(fmaf(di, acc.w, bb.w), 0.f);

    int gl = batch[i] - gFirst;
    atomicAdd(&lp[gl][p * 4 + 0], h.x);
    atomicAdd(&lp[gl][p * 4 + 1], h.y);
    atomicAdd(&lp[gl][p * 4 + 2], h.z);
    atomicAdd(&lp[gl][p * 4 + 3], h.w);
    __syncthreads();

    int gLast = batch[i0 + 31];
    int ng = gLast - gFirst + 1;
    for (int k = threadIdx.x; k < ng * HID; k += 256) {
        float v = lp[k / HID][k % HID];
        if (v != 0.f) atomicAdd(&pooled[(gFirst + k / HID) * HID + (k % HID)], v);
    }
}

// head: mean (counts via binary search) -> relu(@Wc1+bc1) -> sigmoid(@Wc2+bc2)
__global__ void k_head(const float* __restrict__ pooled, const int* __restrict__ batch,
                       const float* __restrict__ Wc1, const float* __restrict__ bc1,
                       const float* __restrict__ Wc2, const float* __restrict__ bc2,
                       float* __restrict__ out) {
    int g = blockIdx.x * blockDim.x + threadIdx.x;
    if (g >= N_GRAPHS) return;
    int lo = 0, hi = N_NODES;
    while (lo < hi) { int mid = (lo + hi) >> 1; if (batch[mid] < g) lo = mid + 1; else hi = mid; }
    int start = lo;
    hi = N_NODES;
    while (lo < hi) { int mid = (lo + hi) >> 1; if (batch[mid] < g + 1) lo = mid + 1; else hi = mid; }
    int end = lo;
    float inv = 1.0f / fmaxf((float)(end - start), 1.0f);
    float m[HID];
    for (int j = 0; j < HID; ++j) m[j] = pooled[g * HID + j] * inv;
    float hc[16];
    for (int j = 0; j < 16; ++j) {
        float s = bc1[j];
        for (int k = 0; k < HID; ++k) s = fmaf(m[k], Wc1[k * 16 + j], s);
        hc[j] = fmaxf(s, 0.f);
    }
    float s = bc2[0];
    for (int k = 0; k < 16; ++k) s = fmaf(hc[k], Wc2[k], s);
    out[g] = 1.0f / (1.0f + expf(-s));
}

// ---------------- launch ----------------

extern "C" void kernel_launch(void* const* d_in, const int* in_sizes, int n_in,
                              void* d_out, int out_size, void* d_ws, size_t ws_size,
                              hipStream_t stream) {
    const int*   ids  = (const int*)d_in[0];
    const int*   src  = (const int*)d_in[1];
    const int*   dst  = ((const int*)d_in[1]) + N_EDGES;
    const int*   batch = (const int*)d_in[2];
    const float* emb  = (const float*)d_in[3];
    const float* W1   = (const float*)d_in[4];
    const float* b1   = (const float*)d_in[5];
    const float* W2   = (const float*)d_in[6];
    const float* b2   = (const float*)d_in[7];
    const float* Wc1  = (const float*)d_in[8];
    const float* bc1  = (const float*)d_in[9];
    const float* Wc2  = (const float*)d_in[10];
    const float* bc2  = (const float*)d_in[11];
    float* out = (float*)d_out;

    // workspace layout — int-element offsets; all sections multiples of 4 ints.
    int* W = (int*)d_ws;
    size_t o = 0;
    uint2* Y2h      = (uint2*)(W + o);        o += 1600000;
    int*   binned   = W + o;                  o += N_EDGES;
    int*   ssrc     = W + o;                  o += NBUCK * MAXBE;
    int2*  nodeinfo = (int2*)(W + o);         o += 2 * N_NODES;
    int4*  nmeta    = (int4*)(W + o);         o += 4 * N_NODES;
    int*   counts   = W + o;                  o += NCHUNK * NBUCK + 1;
    o = (o + 3) & ~(size_t)3;
    int*   locg     = W + o;                  o += NCHUNK * NBUCK;
    o = (o + 3) & ~(size_t)3;
    float* table    = (float*)(W + o);        o += NUM_TYPES * HID;
    float* pooled   = (float*)(W + o);

    const int B = 256;
    const int gNode8 = (N_NODES * 8) / B;       // exact: 3125

    k_bin<<<NCHUNK + 2, 512, 0, stream>>>(src, dst, binned, counts, locg,
                                          emb, W1, table, pooled);
    k_csr<<<NBUCK, 512, 0, stream>>>(binned, counts, locg, ids, ssrc, nodeinfo, nmeta);
    k_gather1<<<gNode8, B, 0, stream>>>(nodeinfo, nmeta, table, ssrc, b1, W2, Y2h);
    k_gather2<<<gNode8, B, 0, stream>>>((const uint2*)Y2h, nmeta, ssrc, b2, batch, pooled);
    k_head<<<1, N_GRAPHS, 0, stream>>>(pooled, batch, Wc1, bc1, Wc2, bc2, out);
}